// Round 19
// baseline (130.709 us; speedup 1.0000x reference)
//
#include <hip/hip_runtime.h>
#include <hip/hip_bf16.h>
#include <math.h>

#define N_TOK 4096
#define DIM   1024

typedef __attribute__((ext_vector_type(8))) short s16x8;
typedef __attribute__((ext_vector_type(4))) float f32x4;
typedef __attribute__((ext_vector_type(8))) float f32x8;
typedef __attribute__((ext_vector_type(4))) int   i32x4;

#define SM_SCALE 3990.0f     // M = exp(tanh(s)/32)-1, |M|<=0.03177 -> |q|<=126.7
#define SV_SCALE 18.0f       // v ~ N(0,1); 127/18 = 7.05 sigma clip
#define SQ_SCALE 18.0f       // q,k ~ N(0,1); 7 sigma clip
#define PV_DEQ   (1.0f / (SM_SCALE * SV_SCALE))
#define QK_DEQ   (1.0f / (SQ_SCALE * SQ_SCALE))

__device__ inline short to_bf16(float f) {
  union { float f; unsigned u; } v; v.f = f;
  unsigned r = v.u + 0x7FFFu + ((v.u >> 16) & 1u);   // RNE
  return (short)(r >> 16);
}

__device__ inline float bf2f(short s) {
  union { unsigned u; float f; } v; v.u = ((unsigned)(unsigned short)s) << 16;
  return v.f;
}

__device__ inline void gload16(const void* g, void* l) {
  __builtin_amdgcn_global_load_lds(
      (const __attribute__((address_space(1))) unsigned int*)g,
      (__attribute__((address_space(3))) unsigned int*)l, 16, 0, 0);
}

// ---------------- cast fp32 -> bf16 ----------------
__global__ void cast_bf16_kernel(const float* __restrict__ in, short* __restrict__ out, int n) {
  int i = (blockIdx.x * blockDim.x + threadIdx.x) * 4;
  if (i >= n) return;
  float4 v = *reinterpret_cast<const float4*>(in + i);
  short4 o;
  o.x = to_bf16(v.x); o.y = to_bf16(v.y); o.z = to_bf16(v.z); o.w = to_bf16(v.w);
  *reinterpret_cast<short4*>(out + i) = o;
}

// ------- transpose + cast (3 weights in one launch via blockIdx.z) -------
__global__ void transpose_cast3_kernel(const float* __restrict__ Wq, const float* __restrict__ Wk,
                                       const float* __restrict__ Wv, short* __restrict__ WqkT,
                                       short* __restrict__ WvT) {
  __shared__ float tile[32][33];
  const float* in  = (blockIdx.z == 0) ? Wq : (blockIdx.z == 1) ? Wk : Wv;
  short* out = (blockIdx.z == 0) ? WqkT : (blockIdx.z == 1) ? (WqkT + DIM * DIM) : WvT;
  int bx = blockIdx.x * 32, by = blockIdx.y * 32;
  int tx = threadIdx.x, ty = threadIdx.y;   // block (32,8)
  #pragma unroll
  for (int i = 0; i < 32; i += 8)
    tile[ty + i][tx] = in[(size_t)(by + ty + i) * DIM + (bx + tx)];
  __syncthreads();
  #pragma unroll
  for (int i = 0; i < 32; i += 8)
    out[(size_t)(bx + ty + i) * DIM + (by + tx)] = to_bf16(tile[tx][ty + i]);
}

__device__ inline float fast_tanh(float x) {
  float e = __expf(2.0f * x);
  return 1.0f - 2.0f / (e + 1.0f);
}

__device__ inline signed char q8(float x, float s) {
  int q = __float2int_rn(x * s);
  q = q > 127 ? 127 : (q < -127 ? -127 : q);
  return (signed char)q;
}

// ====== fused projections: ONE dispatch, 768 blocks (3/CU over all 256 CUs) =========
// blocks [0,512): q|k = xb @ WqkT^T + {bq|bk} -> int8 [4096][2048] (scale SQ)
// blocks [512,768): vT = WvT @ xb^T + bv[row] -> int8 [1024][4096] + colsum(v) f32
__global__ __launch_bounds__(256, 4)
void proj_all(const short* __restrict__ xb, const short* __restrict__ WqkT,
              const short* __restrict__ WvT,
              const float* __restrict__ bq, const float* __restrict__ bk,
              const float* __restrict__ bv,
              signed char* __restrict__ qk8, signed char* __restrict__ v8,
              float* __restrict__ colsumV)
{
  __shared__ short As[128 * 64];
  __shared__ short Bs[128 * 64];
  const int t    = threadIdx.x;
  const int lane = t & 63;
  const int wid  = t >> 6;          // 4 waves: 2(M) x 2(N)
  const int wr   = wid >> 1, wc = wid & 1;
  const int l15  = lane & 15, l4 = lane >> 4;

  const int lin  = blockIdx.x;
  const bool isv = (lin >= 512);
  const int sub  = isv ? (lin - 512) : lin;
  const int s    = isv ? ((sub & 7) * 32 + (sub >> 3)) : ((sub & 7) * 64 + (sub >> 3));
  const int bxx  = isv ? (s & 31) : (s & 15);
  const int byy  = isv ? (s >> 5) : (s >> 4);

  const short* A = isv ? WvT : xb;
  const short* B = isv ? xb  : WqkT;

  const int srow = t >> 3;
  const int sch  = ((t & 7) ^ (srow & 7)) * 8;
  const short* gA = A + (size_t)(byy * 128 + srow) * DIM + sch;
  const short* gB = B + (size_t)(bxx * 128 + srow) * DIM + sch;
  const size_t r1 = (size_t)32 * DIM, r2 = (size_t)64 * DIM, r3 = (size_t)96 * DIM;
  short* ldsA = &As[t * 8];
  short* ldsB = &Bs[t * 8];

  const int x7 = l15 & 7;
  const int abase0 = (wr * 64 + l15) * 64 + (l4 ^ x7) * 8;
  const int abase1 = abase0 ^ 32;
  const int bbase0 = (wc * 64 + l15) * 64 + (l4 ^ x7) * 8;
  const int bbase1 = bbase0 ^ 32;

  f32x4 acc[4][4];
  #pragma unroll
  for (int m = 0; m < 4; ++m)
    #pragma unroll
    for (int n = 0; n < 4; ++n)
      acc[m][n] = f32x4{0.f, 0.f, 0.f, 0.f};

  for (int kt = 0; kt < 16; ++kt) {
    gload16(gA,      ldsA);
    gload16(gA + r1, ldsA + 2048);
    gload16(gA + r2, ldsA + 4096);
    gload16(gA + r3, ldsA + 6144);
    gload16(gB,      ldsB);
    gload16(gB + r1, ldsB + 2048);
    gload16(gB + r2, ldsB + 4096);
    gload16(gB + r3, ldsB + 6144);
    gA += 64; gB += 64;
    __syncthreads();
    {
      s16x8 af[4], bf[4];
      #pragma unroll
      for (int m = 0; m < 4; ++m) af[m] = *(const s16x8*)&As[abase0 + m * 1024];
      #pragma unroll
      for (int n = 0; n < 4; ++n) bf[n] = *(const s16x8*)&Bs[bbase0 + n * 1024];
      #pragma unroll
      for (int m = 0; m < 4; ++m)
        #pragma unroll
        for (int n = 0; n < 4; ++n)
          acc[m][n] = __builtin_amdgcn_mfma_f32_16x16x32_bf16(af[m], bf[n], acc[m][n], 0, 0, 0);
    }
    {
      s16x8 af[4], bf[4];
      #pragma unroll
      for (int m = 0; m < 4; ++m) af[m] = *(const s16x8*)&As[abase1 + m * 1024];
      #pragma unroll
      for (int n = 0; n < 4; ++n) bf[n] = *(const s16x8*)&Bs[bbase1 + n * 1024];
      #pragma unroll
      for (int m = 0; m < 4; ++m)
        #pragma unroll
        for (int n = 0; n < 4; ++n)
          acc[m][n] = __builtin_amdgcn_mfma_f32_16x16x32_bf16(af[m], bf[n], acc[m][n], 0, 0, 0);
    }
    __syncthreads();
  }

  const int rbase = byy * 128 + wr * 64;
  const int cbase = bxx * 128 + wc * 64;

  #pragma unroll
  for (int m = 0; m < 4; ++m) {
    #pragma unroll
    for (int r = 0; r < 4; ++r) {
      const int grow = rbase + m * 16 + l4 * 4 + r;
      if (!isv) {
        #pragma unroll
        for (int n = 0; n < 4; ++n) {
          const int gcol = cbase + n * 16 + l15;
          const float bias = (gcol < DIM) ? bq[gcol] : bk[gcol - DIM];
          qk8[(size_t)grow * (2 * DIM) + gcol] = q8(acc[m][n][r] + bias, SQ_SCALE);
        }
      } else {
        const float bias = bv[grow];
        float rs = 0.f;
        #pragma unroll
        for (int n = 0; n < 4; ++n) {
          float val = acc[m][n][r] + bias;
          rs += val;
          v8[(size_t)grow * N_TOK + (cbase + n * 16 + l15)] = q8(val, SV_SCALE);
        }
        rs += __shfl_xor(rs, 1);
        rs += __shfl_xor(rs, 2);
        rs += __shfl_xor(rs, 4);
        rs += __shfl_xor(rs, 8);
        if (l15 == 0) atomicAdd(&colsumV[grow], rs);
      }
    }
  }
}

// ====== int8 P-GEMM (pure-DMA staging, R17-verified): s=(q8 k8^T)/324 ->
// ====== M int8 + rowsum. Epilogue repacked through LDS for full-line stores.
// grid (32,32) = 1024 blocks (4/CU). ld = 2048 bytes, NT=8, BK=128 B.
__global__ __launch_bounds__(256, 4)
void gemm_p_i8(const signed char* __restrict__ A, const signed char* __restrict__ B,
               signed char* __restrict__ C8, float* __restrict__ rowsumM)
{
  __shared__ __align__(16) signed char smem[32768];
  signed char* As = smem;            // 16 KB
  signed char* Bs = smem + 16384;    // 16 KB
  const int t    = threadIdx.x;
  const int lane = t & 63;
  const int wid  = t >> 6;
  const int wr   = wid >> 1, wc = wid & 1;
  const int l15  = lane & 15, l4 = lane >> 4;

  const int lin = (int)blockIdx.y * 32 + blockIdx.x;   // grid (32, 32)
  const int swz = (lin & 7) * 128 + (lin >> 3);
  const int bxx = swz & 31;
  const int byy = swz >> 5;

  const int srow = t >> 3;
  const int sch  = ((t & 7) ^ (srow & 7)) * 16;        // bytes
  const signed char* gA = A + (size_t)(byy * 128 + srow) * (2 * DIM) + sch;
  const signed char* gB = B + (size_t)(bxx * 128 + srow) * (2 * DIM) + sch;
  const size_t r1 = (size_t)32 * (2 * DIM), r2 = (size_t)64 * (2 * DIM),
               r3 = (size_t)96 * (2 * DIM);
  signed char* ldsA = &As[t * 16];
  signed char* ldsB = &Bs[t * 16];

  const int x7 = l15 & 7;
  const int abase0 = (wr * 64 + l15) * 128 + (l4 ^ x7) * 16;
  const int abase1 = abase0 ^ 64;
  const int bbase0 = (wc * 64 + l15) * 128 + (l4 ^ x7) * 16;
  const int bbase1 = bbase0 ^ 64;

  i32x4 acc[4][4];
  #pragma unroll
  for (int m = 0; m < 4; ++m)
    #pragma unroll
    for (int n = 0; n < 4; ++n)
      acc[m][n] = i32x4{0, 0, 0, 0};

  for (int kt = 0; kt < 8; ++kt) {
    gload16(gA,      ldsA);
    gload16(gA + r1, ldsA + 4096);
    gload16(gA + r2, ldsA + 8192);
    gload16(gA + r3, ldsA + 12288);
    gload16(gB,      ldsB);
    gload16(gB + r1, ldsB + 4096);
    gload16(gB + r2, ldsB + 8192);
    gload16(gB + r3, ldsB + 12288);
    gA += 128; gB += 128;
    __syncthreads();
    {
      i32x4 af[4], bf[4];
      #pragma unroll
      for (int m = 0; m < 4; ++m) af[m] = *(const i32x4*)&As[abase0 + m * 2048];
      #pragma unroll
      for (int n = 0; n < 4; ++n) bf[n] = *(const i32x4*)&Bs[bbase0 + n * 2048];
      #pragma unroll
      for (int m = 0; m < 4; ++m)
        #pragma unroll
        for (int n = 0; n < 4; ++n)
          acc[m][n] = __builtin_amdgcn_mfma_i32_16x16x64_i8(af[m], bf[n], acc[m][n], 0, 0, 0);
    }
    {
      i32x4 af[4], bf[4];
      #pragma unroll
      for (int m = 0; m < 4; ++m) af[m] = *(const i32x4*)&As[abase1 + m * 2048];
      #pragma unroll
      for (int n = 0; n < 4; ++n) bf[n] = *(const i32x4*)&Bs[bbase1 + n * 2048];
      #pragma unroll
      for (int m = 0; m < 4; ++m)
        #pragma unroll
        for (int n = 0; n < 4; ++n)
          acc[m][n] = __builtin_amdgcn_mfma_i32_16x16x64_i8(af[m], bf[n], acc[m][n], 0, 0, 0);
    }
    __syncthreads();
  }

  // ---- epilogue: compute M, rowsum; repack C-tile in LDS; coalesced store ----
  signed char* ctile = As;   // 128x128 bytes = 16 KB (staging done)
  #pragma unroll
  for (int m = 0; m < 4; ++m) {
    #pragma unroll
    for (int r = 0; r < 4; ++r) {
      const int lrow = wr * 64 + m * 16 + l4 * 4 + r;       // 0..127 in tile
      const int grow = byy * 128 + lrow;
      float rs = 0.f;
      #pragma unroll
      for (int n = 0; n < 4; ++n) {
        float sc = (float)acc[m][n][r] * QK_DEQ;
        float Mv = __expf(fast_tanh(sc) * 0.03125f) - 1.0f;
        int q = __float2int_rn(Mv * SM_SCALE);
        q = q > 127 ? 127 : (q < -127 ? -127 : q);
        rs += (float)q;
        ctile[lrow * 128 + (wc * 64 + n * 16 + l15)] = (signed char)q;
      }
      rs += __shfl_xor(rs, 1);
      rs += __shfl_xor(rs, 2);
      rs += __shfl_xor(rs, 4);
      rs += __shfl_xor(rs, 8);
      if (l15 == 0) atomicAdd(&rowsumM[grow], rs);   // rowsum of M in SM units
    }
  }
  __syncthreads();
  // thread t stores 64 contiguous bytes (4 x 16B); 4 consecutive lanes = 64B line
  {
    const int row = t >> 1;                  // 2 threads per 128-B row
    const int c0  = (t & 1) * 64;
    signed char* dst = C8 + (size_t)(byy * 128 + row) * N_TOK + bxx * 128 + c0;
    const signed char* src = &ctile[row * 128 + c0];
    #pragma unroll
    for (int c = 0; c < 4; ++c)
      *(i32x4*)(dst + c * 16) = *(const i32x4*)(src + c * 16);
  }
}

// ====== int8 PV GEMM (pure-DMA staging), split-K=4: S = M_i8 @ v_i8^T ======
// mode1: part[kc] = bf16(S*PV_DEQ) via LDS-repacked coalesced store.
__global__ __launch_bounds__(256, 4)
void gemm_pv_i8(const signed char* __restrict__ A, const signed char* __restrict__ B,
                const float* __restrict__ rowsumM, float* __restrict__ outF,
                short* __restrict__ part, int mode)
{
  __shared__ __align__(16) signed char smem[32768];
  signed char* As = smem;
  signed char* Bs = smem + 16384;
  const int t    = threadIdx.x;
  const int lane = t & 63;
  const int wid  = t >> 6;
  const int wr   = wid >> 1, wc = wid & 1;
  const int l15  = lane & 15, l4 = lane >> 4;

  const int nx = gridDim.x, ny = gridDim.y;          // (8, 32, 4)
  int lin = ((int)blockIdx.z * ny + blockIdx.y) * nx + blockIdx.x;
  const int tot = nx * ny * (int)gridDim.z;
  int swz = (lin & 7) * (tot >> 3) + (lin >> 3);
  const int bxx = swz % nx; swz /= nx;
  const int byy = swz % ny;
  const int kc  = swz / ny;
  const int koff = kc * 1024;                        // 8 tiles x 128 bytes

  const int srow = t >> 3;
  const int sch  = ((t & 7) ^ (srow & 7)) * 16;      // bytes
  const signed char* gA = A + (size_t)(byy * 128 + srow) * 4096 + koff + sch;
  const signed char* gB = B + (size_t)(bxx * 128 + srow) * 4096 + koff + sch;
  const size_t r1 = (size_t)32 * 4096, r2 = (size_t)64 * 4096, r3 = (size_t)96 * 4096;
  signed char* ldsA = &As[t * 16];
  signed char* ldsB = &Bs[t * 16];

  const int x7 = l15 & 7;
  const int abase0 = (wr * 64 + l15) * 128 + (l4 ^ x7) * 16;
  const int abase1 = abase0 ^ 64;
  const int bbase0 = (wc * 64 + l15) * 128 + (l4 ^ x7) * 16;
  const int bbase1 = bbase0 ^ 64;

  i32x4 acc[4][4];
  #pragma unroll
  for (int m = 0; m < 4; ++m)
    #pragma unroll
    for (int n = 0; n < 4; ++n)
      acc[m][n] = i32x4{0, 0, 0, 0};

  for (int kt = 0; kt < 8; ++kt) {
    gload16(gA,      ldsA);
    gload16(gA + r1, ldsA + 4096);
    gload16(gA + r2, ldsA + 8192);
    gload16(gA + r3, ldsA + 12288);
    gload16(gB,      ldsB);
    gload16(gB + r1, ldsB + 4096);
    gload16(gB + r2, ldsB + 8192);
    gload16(gB + r3, ldsB + 12288);
    gA += 128; gB += 128;
    __syncthreads();
    {
      i32x4 af[4], bf[4];
      #pragma unroll
      for (int m = 0; m < 4; ++m) af[m] = *(const i32x4*)&As[abase0 + m * 2048];
      #pragma unroll
      for (int n = 0; n < 4; ++n) bf[n] = *(const i32x4*)&Bs[bbase0 + n * 2048];
      #pragma unroll
      for (int m = 0; m < 4; ++m)
        #pragma unroll
        for (int n = 0; n < 4; ++n)
          acc[m][n] = __builtin_amdgcn_mfma_i32_16x16x64_i8(af[m], bf[n], acc[m][n], 0, 0, 0);
    }
    {
      i32x4 af[4], bf[4];
      #pragma unroll
      for (int m = 0; m < 4; ++m) af[m] = *(const i32x4*)&As[abase1 + m * 2048];
      #pragma unroll
      for (int n = 0; n < 4; ++n) bf[n] = *(const i32x4*)&Bs[bbase1 + n * 2048];
      #pragma unroll
      for (int m = 0; m < 4; ++m)
        #pragma unroll
        for (int n = 0; n < 4; ++n)
          acc[m][n] = __builtin_amdgcn_mfma_i32_16x16x64_i8(af[m], bf[n], acc[m][n], 0, 0, 0);
    }
    __syncthreads();
  }

  const int rbase = byy * 128 + wr * 64;
  const int cbase = bxx * 128 + wc * 64;

  if (mode) {
    // repack bf16 C-tile (128 rows x 128 cols shorts = 32 KB) then coalesced store
    short* ctile = (short*)smem;
    #pragma unroll
    for (int m = 0; m < 4; ++m)
      #pragma unroll
      for (int r = 0; r < 4; ++r) {
        const int lrow = wr * 64 + m * 16 + l4 * 4 + r;
        #pragma unroll
        for (int n = 0; n < 4; ++n)
          ctile[lrow * 128 + (wc * 64 + n * 16 + l15)] =
              to_bf16((float)acc[m][n][r] * PV_DEQ);
      }
    __syncthreads();
    short* pdst = part + (size_t)kc * (N_TOK * DIM);
    const int row = t >> 1;                  // 2 threads per 256-B row
    const int c0  = (t & 1) * 64;            // shorts
    short* dst = pdst + (size_t)(byy * 128 + row) * DIM + bxx * 128 + c0;
    const short* src = &ctile[row * 128 + c0];
    #pragma unroll
    for (int c = 0; c < 8; ++c)
      *(i32x4*)(dst + c * 8) = *(const i32x4*)(src + c * 8);
  } else {
    #pragma unroll
    for (int m = 0; m < 4; ++m)
      #pragma unroll
      for (int r = 0; r < 4; ++r) {
        const int grow = rbase + m * 16 + l4 * 4 + r;
        const float invl = 1.0f / (4096.0f + rowsumM[grow] * (1.0f / SM_SCALE));
        #pragma unroll
        for (int n = 0; n < 4; ++n)
          atomicAdd(&outF[(size_t)grow * DIM + (cbase + n * 16 + l15)],
                    (float)acc[m][n][r] * PV_DEQ * invl);
      }
  }
}

// -------- reduce: out = (colsumV[col] + p0+p1+p2+p3) / l[row] --------
__global__ void reduce_pv(const short* __restrict__ part, const float* __restrict__ rowsumM,
                          const float* __restrict__ colsumV, float* __restrict__ out) {
  const int i = blockIdx.x * blockDim.x + threadIdx.x;   // 8-elem group index
  const int base = i * 8;
  const int row = base >> 10, col0 = base & 1023;
  const s16x8 a = ((const s16x8*)(part))[i];
  const s16x8 b = ((const s16x8*)(part + (size_t)N_TOK * DIM))[i];
  const s16x8 c = ((const s16x8*)(part + (size_t)2 * N_TOK * DIM))[i];
  const s16x8 d = ((const s16x8*)(part + (size_t)3 * N_TOK * DIM))[i];
  const float invl = 1.0f / (4096.0f + rowsumM[row] * (1.0f / SM_SCALE));
  f32x8 o;
  #pragma unroll
  for (int j = 0; j < 8; ++j)
    o[j] = (colsumV[col0 + j] + bf2f(a[j]) + bf2f(b[j]) + bf2f(c[j]) + bf2f(d[j])) * invl;
  *reinterpret_cast<f32x8*>(out + base) = o;
}

// -------- mode0 only: out[i][d] = colsumV[d] / l[i] (PV then atomicAdds on top) ------
__global__ void init_out(const float* __restrict__ rowsumM, const float* __restrict__ colsumV,
                         float* __restrict__ out) {
  const int i = blockIdx.x * blockDim.x + threadIdx.x;
  out[i] = colsumV[i & 1023] / (4096.0f + rowsumM[i >> 10] * (1.0f / SM_SCALE));
}

extern "C" void kernel_launch(void* const* d_in, const int* in_sizes, int n_in,
                              void* d_out, int out_size, void* d_ws, size_t ws_size,
                              hipStream_t stream) {
  const float* x  = (const float*)d_in[0];
  const float* Wq = (const float*)d_in[1];
  const float* bq = (const float*)d_in[2];
  const float* Wk = (const float*)d_in[3];
  const float* bk = (const float*)d_in[4];
  const float* Wv = (const float*)d_in[5];
  const float* bv = (const float*)d_in[6];
  float* out = (float*)d_out;

  char* ws = (char*)d_ws;
  short* xb        = (short*)(ws);                   //  8 MB  x bf16 [4096][1024]
  signed char* qk8 = (signed char*)(ws + (8ull  << 20)); // 8 MB q|k int8 [4096][2048]
  signed char* v8  = (signed char*)(ws + (16ull << 20)); // 4 MB v^T int8 [1024][4096]
  short* WqkT      = (short*)(ws + (20ull << 20));   //  4 MB  [2048][1024]
  short* WvT       = (short*)(ws + (24ull << 20));   //  2 MB
  float* rowsumM   = (float*)(ws + (26ull << 20));   // 16 KB
  float* colsumV   = rowsumM + N_TOK;                //  4 KB
  signed char* M8  = (signed char*)(ws + (27ull << 20)); // 16 MB M int8 [4096][4096]
  short* part      = (short*)(ws + (43ull << 20));   // 33.5 MB 4x[4096][1024] bf16

  const size_t need = (43ull << 20) + 4ull * N_TOK * DIM * sizeof(short);
  const int mode = (ws_size >= need) ? 1 : 0;

  hipMemsetAsync(rowsumM, 0, (N_TOK + DIM) * sizeof(float), stream);

  cast_bf16_kernel<<<(N_TOK * DIM / 4 + 255) / 256, 256, 0, stream>>>(x, xb, N_TOK * DIM);
  transpose_cast3_kernel<<<dim3(DIM / 32, DIM / 32, 3), dim3(32, 8), 0, stream>>>(
      Wq, Wk, Wv, WqkT, WvT);

  dim3 blk(256);
  // fused projections: q|k int8 (512 blocks) + vT int8 (256 blocks) in one dispatch
  proj_all<<<dim3(768), blk, 0, stream>>>(
      xb, WqkT, WvT, bq, bk, bv, qk8, v8, colsumV);
  // M = exp(tanh((q8 k8^T)/324)/32)-1 -> int8 + rowsum   (grid 32x32 = 1024, 4/CU)
  gemm_p_i8<<<dim3(32, 32), blk, 0, stream>>>(qk8, qk8 + DIM, M8, rowsumM);
  // PV int8 split-K=4   (grid 8 x 32 x 4 = 1024, 4 blocks/CU)
  if (!mode)
    init_out<<<dim3(N_TOK * DIM / 256), blk, 0, stream>>>(rowsumM, colsumV, out);
  gemm_pv_i8<<<dim3(8, 32, 4), blk, 0, stream>>>(M8, v8, rowsumM, out, part, mode);
  if (mode)
    reduce_pv<<<dim3(N_TOK * DIM / 8 / 256), blk, 0, stream>>>(part, rowsumM, colsumV, out);
}

// Round 20
// 123.249 us; speedup vs baseline: 1.0605x; 1.0605x over previous
//
#include <hip/hip_runtime.h>
#include <hip/hip_bf16.h>
#include <math.h>

#define N_TOK 4096
#define DIM   1024

typedef __attribute__((ext_vector_type(8))) short s16x8;
typedef __attribute__((ext_vector_type(4))) float f32x4;
typedef __attribute__((ext_vector_type(8))) float f32x8;
typedef __attribute__((ext_vector_type(4))) int   i32x4;

#define SM_SCALE 3990.0f     // M = exp(tanh(s)/32)-1, |M|<=0.03177 -> |q|<=126.7
#define SV_SCALE 18.0f       // v ~ N(0,1); 127/18 = 7.05 sigma clip
#define SQ_SCALE 18.0f       // q,k ~ N(0,1); 7 sigma clip
#define PV_DEQ   (1.0f / (SM_SCALE * SV_SCALE))
#define QK_DEQ   (1.0f / (SQ_SCALE * SQ_SCALE))

__device__ inline short to_bf16(float f) {
  union { float f; unsigned u; } v; v.f = f;
  unsigned r = v.u + 0x7FFFu + ((v.u >> 16) & 1u);   // RNE
  return (short)(r >> 16);
}

__device__ inline float bf2f(short s) {
  union { unsigned u; float f; } v; v.u = ((unsigned)(unsigned short)s) << 16;
  return v.f;
}

__device__ inline void gload16(const void* g, void* l) {
  __builtin_amdgcn_global_load_lds(
      (const __attribute__((address_space(1))) unsigned int*)g,
      (__attribute__((address_space(3))) unsigned int*)l, 16, 0, 0);
}

// ---------------- cast fp32 -> bf16 ----------------
__global__ void cast_bf16_kernel(const float* __restrict__ in, short* __restrict__ out, int n) {
  int i = (blockIdx.x * blockDim.x + threadIdx.x) * 4;
  if (i >= n) return;
  float4 v = *reinterpret_cast<const float4*>(in + i);
  short4 o;
  o.x = to_bf16(v.x); o.y = to_bf16(v.y); o.z = to_bf16(v.z); o.w = to_bf16(v.w);
  *reinterpret_cast<short4*>(out + i) = o;
}

// ------- transpose + cast (3 weights in one launch via blockIdx.z) -------
__global__ void transpose_cast3_kernel(const float* __restrict__ Wq, const float* __restrict__ Wk,
                                       const float* __restrict__ Wv, short* __restrict__ WqkT,
                                       short* __restrict__ WvT) {
  __shared__ float tile[32][33];
  const float* in  = (blockIdx.z == 0) ? Wq : (blockIdx.z == 1) ? Wk : Wv;
  short* out = (blockIdx.z == 0) ? WqkT : (blockIdx.z == 1) ? (WqkT + DIM * DIM) : WvT;
  int bx = blockIdx.x * 32, by = blockIdx.y * 32;
  int tx = threadIdx.x, ty = threadIdx.y;   // block (32,8)
  #pragma unroll
  for (int i = 0; i < 32; i += 8)
    tile[ty + i][tx] = in[(size_t)(by + ty + i) * DIM + (bx + tx)];
  __syncthreads();
  #pragma unroll
  for (int i = 0; i < 32; i += 8)
    out[(size_t)(bx + ty + i) * DIM + (by + tx)] = to_bf16(tile[tx][ty + i]);
}

__device__ inline float fast_tanh(float x) {
  float e = __expf(2.0f * x);
  return 1.0f - 2.0f / (e + 1.0f);
}

__device__ inline signed char q8(float x, float s) {
  int q = __float2int_rn(x * s);
  q = q > 127 ? 127 : (q < -127 ? -127 : q);
  return (signed char)q;
}

// ====== fused projections: ONE dispatch, 768 blocks (3/CU over all 256 CUs) =========
// blocks [0,512): q|k = xb @ WqkT^T + {bq|bk} -> int8 [4096][2048] (scale SQ)
// blocks [512,768): vT = WvT @ xb^T + bv[row] -> int8 [1024][4096] + colsum(v) f32
__global__ __launch_bounds__(256, 4)
void proj_all(const short* __restrict__ xb, const short* __restrict__ WqkT,
              const short* __restrict__ WvT,
              const float* __restrict__ bq, const float* __restrict__ bk,
              const float* __restrict__ bv,
              signed char* __restrict__ qk8, signed char* __restrict__ v8,
              float* __restrict__ colsumV)
{
  __shared__ short As[128 * 64];
  __shared__ short Bs[128 * 64];
  const int t    = threadIdx.x;
  const int lane = t & 63;
  const int wid  = t >> 6;          // 4 waves: 2(M) x 2(N)
  const int wr   = wid >> 1, wc = wid & 1;
  const int l15  = lane & 15, l4 = lane >> 4;

  const int lin  = blockIdx.x;
  const bool isv = (lin >= 512);
  const int sub  = isv ? (lin - 512) : lin;
  const int s    = isv ? ((sub & 7) * 32 + (sub >> 3)) : ((sub & 7) * 64 + (sub >> 3));
  const int bxx  = isv ? (s & 31) : (s & 15);
  const int byy  = isv ? (s >> 5) : (s >> 4);

  const short* A = isv ? WvT : xb;
  const short* B = isv ? xb  : WqkT;

  const int srow = t >> 3;
  const int sch  = ((t & 7) ^ (srow & 7)) * 8;
  const short* gA = A + (size_t)(byy * 128 + srow) * DIM + sch;
  const short* gB = B + (size_t)(bxx * 128 + srow) * DIM + sch;
  const size_t r1 = (size_t)32 * DIM, r2 = (size_t)64 * DIM, r3 = (size_t)96 * DIM;
  short* ldsA = &As[t * 8];
  short* ldsB = &Bs[t * 8];

  const int x7 = l15 & 7;
  const int abase0 = (wr * 64 + l15) * 64 + (l4 ^ x7) * 8;
  const int abase1 = abase0 ^ 32;
  const int bbase0 = (wc * 64 + l15) * 64 + (l4 ^ x7) * 8;
  const int bbase1 = bbase0 ^ 32;

  f32x4 acc[4][4];
  #pragma unroll
  for (int m = 0; m < 4; ++m)
    #pragma unroll
    for (int n = 0; n < 4; ++n)
      acc[m][n] = f32x4{0.f, 0.f, 0.f, 0.f};

  for (int kt = 0; kt < 16; ++kt) {
    gload16(gA,      ldsA);
    gload16(gA + r1, ldsA + 2048);
    gload16(gA + r2, ldsA + 4096);
    gload16(gA + r3, ldsA + 6144);
    gload16(gB,      ldsB);
    gload16(gB + r1, ldsB + 2048);
    gload16(gB + r2, ldsB + 4096);
    gload16(gB + r3, ldsB + 6144);
    gA += 64; gB += 64;
    __syncthreads();
    {
      s16x8 af[4], bf[4];
      #pragma unroll
      for (int m = 0; m < 4; ++m) af[m] = *(const s16x8*)&As[abase0 + m * 1024];
      #pragma unroll
      for (int n = 0; n < 4; ++n) bf[n] = *(const s16x8*)&Bs[bbase0 + n * 1024];
      #pragma unroll
      for (int m = 0; m < 4; ++m)
        #pragma unroll
        for (int n = 0; n < 4; ++n)
          acc[m][n] = __builtin_amdgcn_mfma_f32_16x16x32_bf16(af[m], bf[n], acc[m][n], 0, 0, 0);
    }
    {
      s16x8 af[4], bf[4];
      #pragma unroll
      for (int m = 0; m < 4; ++m) af[m] = *(const s16x8*)&As[abase1 + m * 1024];
      #pragma unroll
      for (int n = 0; n < 4; ++n) bf[n] = *(const s16x8*)&Bs[bbase1 + n * 1024];
      #pragma unroll
      for (int m = 0; m < 4; ++m)
        #pragma unroll
        for (int n = 0; n < 4; ++n)
          acc[m][n] = __builtin_amdgcn_mfma_f32_16x16x32_bf16(af[m], bf[n], acc[m][n], 0, 0, 0);
    }
    __syncthreads();
  }

  const int rbase = byy * 128 + wr * 64;
  const int cbase = bxx * 128 + wc * 64;

  #pragma unroll
  for (int m = 0; m < 4; ++m) {
    #pragma unroll
    for (int r = 0; r < 4; ++r) {
      const int grow = rbase + m * 16 + l4 * 4 + r;
      if (!isv) {
        #pragma unroll
        for (int n = 0; n < 4; ++n) {
          const int gcol = cbase + n * 16 + l15;
          const float bias = (gcol < DIM) ? bq[gcol] : bk[gcol - DIM];
          qk8[(size_t)grow * (2 * DIM) + gcol] = q8(acc[m][n][r] + bias, SQ_SCALE);
        }
      } else {
        const float bias = bv[grow];
        float rs = 0.f;
        #pragma unroll
        for (int n = 0; n < 4; ++n) {
          float val = acc[m][n][r] + bias;
          rs += val;
          v8[(size_t)grow * N_TOK + (cbase + n * 16 + l15)] = q8(val, SV_SCALE);
        }
        rs += __shfl_xor(rs, 1);
        rs += __shfl_xor(rs, 2);
        rs += __shfl_xor(rs, 4);
        rs += __shfl_xor(rs, 8);
        if (l15 == 0) atomicAdd(&colsumV[grow], rs);
      }
    }
  }
}

// ====== int8 P-GEMM: s = (q8 k8^T)/324, M = exp(tanh(s)/32)-1 -> int8 + rowsum ======
// A = qk8 (q cols [0,1024)), B = qk8+1024 (k cols). ld = 2048 bytes. NT=8, BK=128 B.
// grid (32,32) = 1024 blocks (4/CU). Pure-DMA staging (R17-verified, 123.9 us total).
__global__ __launch_bounds__(256, 4)
void gemm_p_i8(const signed char* __restrict__ A, const signed char* __restrict__ B,
               signed char* __restrict__ C8, float* __restrict__ rowsumM)
{
  __shared__ __align__(16) signed char As[128 * 128];
  __shared__ __align__(16) signed char Bs[128 * 128];
  const int t    = threadIdx.x;
  const int lane = t & 63;
  const int wid  = t >> 6;
  const int wr   = wid >> 1, wc = wid & 1;
  const int l15  = lane & 15, l4 = lane >> 4;

  const int lin = (int)blockIdx.y * 32 + blockIdx.x;   // grid (32, 32)
  const int swz = (lin & 7) * 128 + (lin >> 3);
  const int bxx = swz & 31;
  const int byy = swz >> 5;

  const int srow = t >> 3;
  const int sch  = ((t & 7) ^ (srow & 7)) * 16;        // bytes
  const signed char* gA = A + (size_t)(byy * 128 + srow) * (2 * DIM) + sch;
  const signed char* gB = B + (size_t)(bxx * 128 + srow) * (2 * DIM) + sch;
  const size_t r1 = (size_t)32 * (2 * DIM), r2 = (size_t)64 * (2 * DIM),
               r3 = (size_t)96 * (2 * DIM);
  signed char* ldsA = &As[t * 16];
  signed char* ldsB = &Bs[t * 16];

  const int x7 = l15 & 7;
  const int abase0 = (wr * 64 + l15) * 128 + (l4 ^ x7) * 16;
  const int abase1 = abase0 ^ 64;
  const int bbase0 = (wc * 64 + l15) * 128 + (l4 ^ x7) * 16;
  const int bbase1 = bbase0 ^ 64;

  i32x4 acc[4][4];
  #pragma unroll
  for (int m = 0; m < 4; ++m)
    #pragma unroll
    for (int n = 0; n < 4; ++n)
      acc[m][n] = i32x4{0, 0, 0, 0};

  for (int kt = 0; kt < 8; ++kt) {
    gload16(gA,      ldsA);
    gload16(gA + r1, ldsA + 4096);
    gload16(gA + r2, ldsA + 8192);
    gload16(gA + r3, ldsA + 12288);
    gload16(gB,      ldsB);
    gload16(gB + r1, ldsB + 4096);
    gload16(gB + r2, ldsB + 8192);
    gload16(gB + r3, ldsB + 12288);
    gA += 128; gB += 128;
    __syncthreads();
    {
      i32x4 af[4], bf[4];
      #pragma unroll
      for (int m = 0; m < 4; ++m) af[m] = *(const i32x4*)&As[abase0 + m * 2048];
      #pragma unroll
      for (int n = 0; n < 4; ++n) bf[n] = *(const i32x4*)&Bs[bbase0 + n * 2048];
      #pragma unroll
      for (int m = 0; m < 4; ++m)
        #pragma unroll
        for (int n = 0; n < 4; ++n)
          acc[m][n] = __builtin_amdgcn_mfma_i32_16x16x64_i8(af[m], bf[n], acc[m][n], 0, 0, 0);
    }
    {
      i32x4 af[4], bf[4];
      #pragma unroll
      for (int m = 0; m < 4; ++m) af[m] = *(const i32x4*)&As[abase1 + m * 2048];
      #pragma unroll
      for (int n = 0; n < 4; ++n) bf[n] = *(const i32x4*)&Bs[bbase1 + n * 2048];
      #pragma unroll
      for (int m = 0; m < 4; ++m)
        #pragma unroll
        for (int n = 0; n < 4; ++n)
          acc[m][n] = __builtin_amdgcn_mfma_i32_16x16x64_i8(af[m], bf[n], acc[m][n], 0, 0, 0);
    }
    __syncthreads();
  }

  const int rbase = byy * 128 + wr * 64;
  const int cbase = bxx * 128 + wc * 64;

  #pragma unroll
  for (int m = 0; m < 4; ++m) {
    #pragma unroll
    for (int r = 0; r < 4; ++r) {
      const int grow = rbase + m * 16 + l4 * 4 + r;
      float rs = 0.f;
      #pragma unroll
      for (int n = 0; n < 4; ++n) {
        float sc = (float)acc[m][n][r] * QK_DEQ;
        float Mv = __expf(fast_tanh(sc) * 0.03125f) - 1.0f;
        int q = __float2int_rn(Mv * SM_SCALE);
        q = q > 127 ? 127 : (q < -127 ? -127 : q);
        rs += (float)q;
        C8[(size_t)grow * N_TOK + (cbase + n * 16 + l15)] = (signed char)q;
      }
      rs += __shfl_xor(rs, 1);
      rs += __shfl_xor(rs, 2);
      rs += __shfl_xor(rs, 4);
      rs += __shfl_xor(rs, 8);
      if (l15 == 0) atomicAdd(&rowsumM[grow], rs);   // rowsum of M in SM units
    }
  }
}

// ============== int8 PV GEMM: S = M_i8 @ v_i8^T, split-K=4, 128^2 tile ==============
__global__ __launch_bounds__(256, 4)
void gemm_pv_i8(const signed char* __restrict__ A, const signed char* __restrict__ B,
                const float* __restrict__ rowsumM, float* __restrict__ outF,
                short* __restrict__ part, int mode)
{
  __shared__ __align__(16) signed char As[128 * 128];
  __shared__ __align__(16) signed char Bs[128 * 128];
  const int t    = threadIdx.x;
  const int lane = t & 63;
  const int wid  = t >> 6;
  const int wr   = wid >> 1, wc = wid & 1;
  const int l15  = lane & 15, l4 = lane >> 4;

  const int nx = gridDim.x, ny = gridDim.y;          // (8, 32, 4)
  int lin = ((int)blockIdx.z * ny + blockIdx.y) * nx + blockIdx.x;
  const int tot = nx * ny * (int)gridDim.z;
  int swz = (lin & 7) * (tot >> 3) + (lin >> 3);
  const int bxx = swz % nx; swz /= nx;
  const int byy = swz % ny;
  const int kc  = swz / ny;
  const int koff = kc * 1024;                        // 8 tiles x 128 bytes

  const int srow = t >> 3;
  const int sch  = ((t & 7) ^ (srow & 7)) * 16;      // bytes
  const signed char* gA = A + (size_t)(byy * 128 + srow) * 4096 + koff + sch;
  const signed char* gB = B + (size_t)(bxx * 128 + srow) * 4096 + koff + sch;
  const size_t r1 = (size_t)32 * 4096, r2 = (size_t)64 * 4096, r3 = (size_t)96 * 4096;
  signed char* ldsA = &As[t * 16];
  signed char* ldsB = &Bs[t * 16];

  const int x7 = l15 & 7;
  const int abase0 = (wr * 64 + l15) * 128 + (l4 ^ x7) * 16;
  const int abase1 = abase0 ^ 64;
  const int bbase0 = (wc * 64 + l15) * 128 + (l4 ^ x7) * 16;
  const int bbase1 = bbase0 ^ 64;

  i32x4 acc[4][4];
  #pragma unroll
  for (int m = 0; m < 4; ++m)
    #pragma unroll
    for (int n = 0; n < 4; ++n)
      acc[m][n] = i32x4{0, 0, 0, 0};

  for (int kt = 0; kt < 8; ++kt) {
    gload16(gA,      ldsA);
    gload16(gA + r1, ldsA + 4096);
    gload16(gA + r2, ldsA + 8192);
    gload16(gA + r3, ldsA + 12288);
    gload16(gB,      ldsB);
    gload16(gB + r1, ldsB + 4096);
    gload16(gB + r2, ldsB + 8192);
    gload16(gB + r3, ldsB + 12288);
    gA += 128; gB += 128;
    __syncthreads();
    {
      i32x4 af[4], bf[4];
      #pragma unroll
      for (int m = 0; m < 4; ++m) af[m] = *(const i32x4*)&As[abase0 + m * 2048];
      #pragma unroll
      for (int n = 0; n < 4; ++n) bf[n] = *(const i32x4*)&Bs[bbase0 + n * 2048];
      #pragma unroll
      for (int m = 0; m < 4; ++m)
        #pragma unroll
        for (int n = 0; n < 4; ++n)
          acc[m][n] = __builtin_amdgcn_mfma_i32_16x16x64_i8(af[m], bf[n], acc[m][n], 0, 0, 0);
    }
    {
      i32x4 af[4], bf[4];
      #pragma unroll
      for (int m = 0; m < 4; ++m) af[m] = *(const i32x4*)&As[abase1 + m * 2048];
      #pragma unroll
      for (int n = 0; n < 4; ++n) bf[n] = *(const i32x4*)&Bs[bbase1 + n * 2048];
      #pragma unroll
      for (int m = 0; m < 4; ++m)
        #pragma unroll
        for (int n = 0; n < 4; ++n)
          acc[m][n] = __builtin_amdgcn_mfma_i32_16x16x64_i8(af[m], bf[n], acc[m][n], 0, 0, 0);
    }
    __syncthreads();
  }

  const int rbase = byy * 128 + wr * 64;
  const int cbase = bxx * 128 + wc * 64;

  if (mode) {
    short* pdst = part + (size_t)kc * (N_TOK * DIM);
    #pragma unroll
    for (int m = 0; m < 4; ++m)
      #pragma unroll
      for (int r = 0; r < 4; ++r) {
        const int grow = rbase + m * 16 + l4 * 4 + r;
        #pragma unroll
        for (int n = 0; n < 4; ++n)
          pdst[(size_t)grow * DIM + (cbase + n * 16 + l15)] = to_bf16((float)acc[m][n][r] * PV_DEQ);
      }
  } else {
    #pragma unroll
    for (int m = 0; m < 4; ++m)
      #pragma unroll
      for (int r = 0; r < 4; ++r) {
        const int grow = rbase + m * 16 + l4 * 4 + r;
        const float invl = 1.0f / (4096.0f + rowsumM[grow] * (1.0f / SM_SCALE));
        #pragma unroll
        for (int n = 0; n < 4; ++n)
          atomicAdd(&outF[(size_t)grow * DIM + (cbase + n * 16 + l15)],
                    (float)acc[m][n][r] * PV_DEQ * invl);
      }
  }
}

// -------- reduce: out = (colsumV[col] + p0+p1+p2+p3) / l[row] --------
__global__ void reduce_pv(const short* __restrict__ part, const float* __restrict__ rowsumM,
                          const float* __restrict__ colsumV, float* __restrict__ out) {
  const int i = blockIdx.x * blockDim.x + threadIdx.x;   // 8-elem group index
  const int base = i * 8;
  const int row = base >> 10, col0 = base & 1023;
  const s16x8 a = ((const s16x8*)(part))[i];
  const s16x8 b = ((const s16x8*)(part + (size_t)N_TOK * DIM))[i];
  const s16x8 c = ((const s16x8*)(part + (size_t)2 * N_TOK * DIM))[i];
  const s16x8 d = ((const s16x8*)(part + (size_t)3 * N_TOK * DIM))[i];
  const float invl = 1.0f / (4096.0f + rowsumM[row] * (1.0f / SM_SCALE));
  f32x8 o;
  #pragma unroll
  for (int j = 0; j < 8; ++j)
    o[j] = (colsumV[col0 + j] + bf2f(a[j]) + bf2f(b[j]) + bf2f(c[j]) + bf2f(d[j])) * invl;
  *reinterpret_cast<f32x8*>(out + base) = o;
}

// -------- mode0 only: out[i][d] = colsumV[d] / l[i] (PV then atomicAdds on top) ------
__global__ void init_out(const float* __restrict__ rowsumM, const float* __restrict__ colsumV,
                         float* __restrict__ out) {
  const int i = blockIdx.x * blockDim.x + threadIdx.x;
  out[i] = colsumV[i & 1023] / (4096.0f + rowsumM[i >> 10] * (1.0f / SM_SCALE));
}

extern "C" void kernel_launch(void* const* d_in, const int* in_sizes, int n_in,
                              void* d_out, int out_size, void* d_ws, size_t ws_size,
                              hipStream_t stream) {
  const float* x  = (const float*)d_in[0];
  const float* Wq = (const float*)d_in[1];
  const float* bq = (const float*)d_in[2];
  const float* Wk = (const float*)d_in[3];
  const float* bk = (const float*)d_in[4];
  const float* Wv = (const float*)d_in[5];
  const float* bv = (const float*)d_in[6];
  float* out = (float*)d_out;

  char* ws = (char*)d_ws;
  short* xb        = (short*)(ws);                   //  8 MB  x bf16 [4096][1024]
  signed char* qk8 = (signed char*)(ws + (8ull  << 20)); // 8 MB q|k int8 [4096][2048]
  signed char* v8  = (signed char*)(ws + (16ull << 20)); // 4 MB v^T int8 [1024][4096]
  short* WqkT      = (short*)(ws + (20ull << 20));   //  4 MB  [2048][1024]
  short* WvT       = (short*)(ws + (24ull << 20));   //  2 MB
  float* rowsumM   = (float*)(ws + (26ull << 20));   // 16 KB
  float* colsumV   = rowsumM + N_TOK;                //  4 KB
  signed char* M8  = (signed char*)(ws + (27ull << 20)); // 16 MB M int8 [4096][4096]
  short* part      = (short*)(ws + (43ull << 20));   // 33.5 MB 4x[4096][1024] bf16

  const size_t need = (43ull << 20) + 4ull * N_TOK * DIM * sizeof(short);
  const int mode = (ws_size >= need) ? 1 : 0;

  hipMemsetAsync(rowsumM, 0, (N_TOK + DIM) * sizeof(float), stream);

  cast_bf16_kernel<<<(N_TOK * DIM / 4 + 255) / 256, 256, 0, stream>>>(x, xb, N_TOK * DIM);
  transpose_cast3_kernel<<<dim3(DIM / 32, DIM / 32, 3), dim3(32, 8), 0, stream>>>(
      Wq, Wk, Wv, WqkT, WvT);

  dim3 blk(256);
  // fused projections: q|k int8 (512 blocks) + vT int8 (256 blocks) in one dispatch
  proj_all<<<dim3(768), blk, 0, stream>>>(
      xb, WqkT, WvT, bq, bk, bv, qk8, v8, colsumV);
  // M = exp(tanh((q8 k8^T)/324)/32)-1 -> int8 + rowsum   (grid 32x32 = 1024, 4/CU)
  gemm_p_i8<<<dim3(32, 32), blk, 0, stream>>>(qk8, qk8 + DIM, M8, rowsumM);
  // PV int8 split-K=4   (grid 8 x 32 x 4 = 1024, 4 blocks/CU)
  if (!mode)
    init_out<<<dim3(N_TOK * DIM / 256), blk, 0, stream>>>(rowsumM, colsumV, out);
  gemm_pv_i8<<<dim3(8, 32, 4), blk, 0, stream>>>(M8, v8, rowsumM, out, part, mode);
  if (mode)
    reduce_pv<<<dim3(N_TOK * DIM / 8 / 256), blk, 0, stream>>>(part, rowsumM, colsumV, out);
}